// Round 11
// baseline (80.040 us; speedup 1.0000x reference)
//
#include <hip/hip_runtime.h>
#include <hip/hip_bf16.h>

#define NUM_CLASS 21
#define IGNORE_L 255
#define EPSF 1e-6f
// Problem dims (fixed by setup_inputs): B=8, D=512, H=W=128 -> HW=16384
#define BATCH 8
#define DCH 512
#define HW 16384
#define NHALF (BATCH * DCH)   // 4096 scatter blocks (pair x half-range)

__device__ __forceinline__ float waveReduce(float v) {
    #pragma unroll
    for (int m = 1; m < 64; m <<= 1) v += __shfl_xor(v, m, 64);
    return v;
}

// Per-element float2 LDS RMW (rows d0,d0+1 packed in one b64 slot).
// R and W adjacent per element; within one element step the 64 lanes hit
// distinct addresses (slot = (lane+16k)&63, same k), so the step is
// race-free; steps are ordered by the wave's in-order DS execution.
// Invalid labels clamp to class 0 with gated +0. ss accumulates f^2 for
// both rows (valid elements only).
__device__ __forceinline__ void rmwq(float2* __restrict__ smw,
                                     int s0, int s1, int s2, int s3,
                                     float4 fa, float4 fb, int4 l, float& ss) {
    {
        const bool v = (unsigned)l.x < NUM_CLASS;
        const int a = (v ? l.x : 0) * 64 + s0;
        const float ga = v ? fa.x : 0.0f, gb = v ? fb.x : 0.0f;
        float2 w = smw[a]; w.x += ga; w.y += gb; smw[a] = w;
        ss = fmaf(ga, fa.x, ss); ss = fmaf(gb, fb.x, ss);
    }
    {
        const bool v = (unsigned)l.y < NUM_CLASS;
        const int a = (v ? l.y : 0) * 64 + s1;
        const float ga = v ? fa.y : 0.0f, gb = v ? fb.y : 0.0f;
        float2 w = smw[a]; w.x += ga; w.y += gb; smw[a] = w;
        ss = fmaf(ga, fa.y, ss); ss = fmaf(gb, fb.y, ss);
    }
    {
        const bool v = (unsigned)l.z < NUM_CLASS;
        const int a = (v ? l.z : 0) * 64 + s2;
        const float ga = v ? fa.z : 0.0f, gb = v ? fb.z : 0.0f;
        float2 w = smw[a]; w.x += ga; w.y += gb; smw[a] = w;
        ss = fmaf(ga, fa.z, ss); ss = fmaf(gb, fb.z, ss);
    }
    {
        const bool v = (unsigned)l.w < NUM_CLASS;
        const int a = (v ? l.w : 0) * 64 + s3;
        const float ga = v ? fa.w : 0.0f, gb = v ? fb.w : 0.0f;
        float2 w = smw[a]; w.x += ga; w.y += gb; smw[a] = w;
        ss = fmaf(ga, fa.w, ss); ss = fmaf(gb, fb.w, ss);
    }
}

// ---------------------------------------------------------------------------
// Fused kernel: blocks [0,8) per-batch counts; blocks [8, 8+NHALF) each
// handle HALF the pixel range of a (b, d0=2*pair) row pair. Half-length
// blocks (~12us) shrink the end-of-grid drain tail vs full-pair blocks.
// Per-wave private LDS copies (no atomics; gfx950 ds_add_f32 ~lane-serial);
// float2 slots amortize DS instrs over 2 rows; 4-deep prefetch ring.
// ---------------------------------------------------------------------------
__global__ __launch_bounds__(256) void car_fused_kernel(
    const float* __restrict__ features, const int* __restrict__ label,
    float* __restrict__ class_sum_part, float* __restrict__ ss_parts,
    float* __restrict__ counts, float* __restrict__ total_parts)
{
    __shared__ float2 sm[4][NUM_CLASS * 64];
    __shared__ float red[4];
    const int t = threadIdx.x;
    const int lane = t & 63;
    const int wave = t >> 6;
    const int s0 = lane;
    const int s1 = (lane + 16) & 63;
    const int s2 = (lane + 32) & 63;
    const int s3 = (lane + 48) & 63;

    float2* __restrict__ smw = &sm[wave][0];
    #pragma unroll
    for (int i = lane; i < NUM_CLASS * 64; i += 64) smw[i] = make_float2(0.f, 0.f);
    // no sync: each wave touches only its own copy until the merge

    if (blockIdx.x < BATCH) {
        // ---- counts path: fa = ones, fb = 0; slot .x accumulates count ----
        const int b = blockIdx.x;
        const int4* __restrict__ lrow = (const int4*)(label + (size_t)b * HW);
        const float4 f1 = {1.f, 1.f, 1.f, 1.f};
        const float4 f0 = {0.f, 0.f, 0.f, 0.f};
        float tv = 0.0f;
        #pragma unroll 2
        for (int i = 0; i < 16; ++i) {
            int4 l = lrow[i * 256 + t];
            rmwq(smw, s0, s1, s2, s3, f1, f0, l, tv);  // tv += 1 per valid
        }
        __syncthreads();
        for (int c = wave; c < NUM_CLASS; c += 4) {
            const float4 vA = *(const float4*)((const float*)&sm[lane >> 5][c * 64] + (lane & 31) * 4);
            const float4 vB = *(const float4*)((const float*)&sm[2 + (lane >> 5)][c * 64] + (lane & 31) * 4);
            float px = (vA.x + vA.z) + (vB.x + vB.z);
            px = waveReduce(px);
            if (lane == 0) counts[b * NUM_CLASS + c] = px;
        }
        tv = waveReduce(tv);
        if (lane == 0) red[wave] = tv;
        __syncthreads();
        if (t == 0) total_parts[b] = red[0] + red[1] + red[2] + red[3];
        return;
    }

    // ---- scatter path: half h of row pair (b, d0), (b, d0+1) ----
    const int r = blockIdx.x - BATCH;          // 0..NHALF-1
    const int pair = r >> 1;
    const int h = r & 1;
    const int b = pair >> 8;
    const int d0 = (pair & 255) * 2;
    const int q0 = h * (HW / 4 / 2);           // starting float4-quad index
    const float4* __restrict__ frow0 = (const float4*)(features + ((size_t)b * DCH + d0) * HW) + q0;
    const float4* __restrict__ frow1 = (const float4*)(features + ((size_t)b * DCH + d0 + 1) * HW) + q0;
    const int4* __restrict__ lrow = (const int4*)(label + (size_t)b * HW) + q0;

    // 4-deep prefetch ring over 8 iterations (named regs to avoid spills).
    float4 A0 = frow0[0 * 256 + t], B0 = frow1[0 * 256 + t];
    float4 A1 = frow0[1 * 256 + t], B1 = frow1[1 * 256 + t];
    float4 A2 = frow0[2 * 256 + t], B2 = frow1[2 * 256 + t];
    float4 A3 = frow0[3 * 256 + t], B3 = frow1[3 * 256 + t];
    int4 L0 = lrow[0 * 256 + t], L1 = lrow[1 * 256 + t];
    int4 L2 = lrow[2 * 256 + t], L3 = lrow[3 * 256 + t];
    float ss = 0.0f;

    rmwq(smw, s0, s1, s2, s3, A0, B0, L0, ss);
    A0 = frow0[4 * 256 + t]; B0 = frow1[4 * 256 + t]; L0 = lrow[4 * 256 + t];
    rmwq(smw, s0, s1, s2, s3, A1, B1, L1, ss);
    A1 = frow0[5 * 256 + t]; B1 = frow1[5 * 256 + t]; L1 = lrow[5 * 256 + t];
    rmwq(smw, s0, s1, s2, s3, A2, B2, L2, ss);
    A2 = frow0[6 * 256 + t]; B2 = frow1[6 * 256 + t]; L2 = lrow[6 * 256 + t];
    rmwq(smw, s0, s1, s2, s3, A3, B3, L3, ss);
    A3 = frow0[7 * 256 + t]; B3 = frow1[7 * 256 + t]; L3 = lrow[7 * 256 + t];
    rmwq(smw, s0, s1, s2, s3, A0, B0, L0, ss);
    rmwq(smw, s0, s1, s2, s3, A1, B1, L1, ss);
    rmwq(smw, s0, s1, s2, s3, A2, B2, L2, ss);
    rmwq(smw, s0, s1, s2, s3, A3, B3, L3, ss);
    __syncthreads();

    // Merge 4 wave-copies x 64 slots per class.
    // Two b128 reads/class cover all 4 copies; .x/.z = row d0, .y/.w = d0+1.
    float* __restrict__ out_base = class_sum_part
        + (size_t)h * (BATCH * NUM_CLASS * DCH)
        + (size_t)b * NUM_CLASS * DCH + d0;
    for (int c = wave; c < NUM_CLASS; c += 4) {
        const float4 vA = *(const float4*)((const float*)&sm[lane >> 5][c * 64] + (lane & 31) * 4);
        const float4 vB = *(const float4*)((const float*)&sm[2 + (lane >> 5)][c * 64] + (lane & 31) * 4);
        float px = (vA.x + vA.z) + (vB.x + vB.z);
        float py = (vA.y + vA.w) + (vB.y + vB.w);
        #pragma unroll
        for (int m = 1; m < 64; m <<= 1) {
            px += __shfl_xor(px, m, 64);
            py += __shfl_xor(py, m, 64);
        }
        if (lane == 0) *(float2*)&out_base[(size_t)c * DCH] = make_float2(px, py);
    }

    ss = waveReduce(ss);
    if (lane == 0) red[wave] = ss;
    __syncthreads();
    if (t == 0) ss_parts[r] = red[0] + red[1] + red[2] + red[3];
}

// ---------------------------------------------------------------------------
// Finalize (1 block, 1024 threads / 16 waves).
//  0: sum ss_parts[4096].
//  A: centers from S = part0+part1; corr = sum cen*(n*cen - 2S); batch-mean cm.
//  C: per-class norms of cm.   D: 21x21 cosine sim -> inter loss.
//  out[0] = (ss + corr)/(total+eps); out[1] = sum relu(sim-.5)/(21+eps).
// ---------------------------------------------------------------------------
__global__ __launch_bounds__(1024) void car_finalize_kernel(
    const float* __restrict__ class_sum_part, const float* __restrict__ counts,
    const float* __restrict__ ss_parts, const float* __restrict__ total_parts,
    float* __restrict__ out)
{
    __shared__ float cm[NUM_CLASS * DCH];
    __shared__ float norms[NUM_CLASS];
    __shared__ float redC[16];
    __shared__ float redS[16];
    __shared__ float redB[16];
    const int t = threadIdx.x;
    const int lane = t & 63;
    const int wave = t >> 6;

    float ssp = 0.0f;
    #pragma unroll
    for (int i = 0; i < NHALF / 1024; ++i) ssp += ss_parts[i * 1024 + t];

    const float* __restrict__ cs0 = class_sum_part;
    const float* __restrict__ cs1 = class_sum_part + (size_t)(BATCH * NUM_CLASS * DCH);

    float corr = 0.0f;
    for (int p = t; p < NUM_CLASS * DCH; p += 1024) {
        const int c = p >> 9;
        float s = 0.0f;
        #pragma unroll
        for (int b = 0; b < BATCH; ++b) {
            const size_t idx = (size_t)b * NUM_CLASS * DCH + p;
            float S = cs0[idx] + cs1[idx];
            float n = counts[b * NUM_CLASS + c];
            float cen = S / (n + EPSF);
            corr += cen * (n * cen - 2.0f * S);
            s += cen;
        }
        cm[p] = s * (1.0f / BATCH);
    }
    corr = waveReduce(corr);
    ssp  = waveReduce(ssp);
    if (lane == 0) { redC[wave] = corr; redS[wave] = ssp; }
    __syncthreads();

    for (int c = wave; c < NUM_CLASS; c += 16) {
        float s = 0.0f;
        #pragma unroll
        for (int k = 0; k < DCH / 64; ++k) {
            float v = cm[c * DCH + k * 64 + lane];
            s += v * v;
        }
        s = waveReduce(s);
        if (lane == 0) norms[c] = fmaxf(sqrtf(s), 1e-12f);
    }
    __syncthreads();

    float interAcc = 0.0f;
    for (int p = wave; p < NUM_CLASS * NUM_CLASS; p += 16) {
        const int c1 = p / NUM_CLASS;
        const int c2 = p % NUM_CLASS;
        if (c1 == c2) continue;
        float s = 0.0f;
        #pragma unroll
        for (int k = 0; k < DCH / 64; ++k)
            s += cm[c1 * DCH + k * 64 + lane] * cm[c2 * DCH + k * 64 + lane];
        s = waveReduce(s);
        if (lane == 0) {
            float sim = s / (norms[c1] * norms[c2]);
            interAcc += fmaxf(sim - 0.5f, 0.0f);
        }
    }
    if (lane == 0) redB[wave] = interAcc;
    __syncthreads();

    if (t == 0) {
        float corrT = 0.0f, interT = 0.0f, ssT = 0.0f, tot = 0.0f;
        #pragma unroll
        for (int w = 0; w < 16; ++w) { corrT += redC[w]; interT += redB[w]; ssT += redS[w]; }
        #pragma unroll
        for (int b = 0; b < BATCH; ++b) tot += total_parts[b];
        out[0] = (ssT + corrT) / (tot + EPSF);
        out[1] = interT / ((float)NUM_CLASS + EPSF);
    }
}

extern "C" void kernel_launch(void* const* d_in, const int* in_sizes, int n_in,
                              void* d_out, int out_size, void* d_ws, size_t ws_size,
                              hipStream_t stream) {
    const float* features = (const float*)d_in[0];
    const int*   label    = (const int*)d_in[1];
    float* out = (float*)d_out;

    // ws layout (floats):
    //   [0 .. 4096)          ss_parts (one per scatter block)
    //   [4096 .. 4104)       total_parts
    //   [4104 .. 4272)       counts (8*21)
    //   [4352 .. 176384)     class_sum_part[2][8][21][512]
    float* ws             = (float*)d_ws;
    float* ss_parts       = ws + 0;
    float* total_parts    = ws + 4096;
    float* counts         = ws + 4104;
    float* class_sum_part = ws + 4352;

    car_fused_kernel<<<NHALF + BATCH, 256, 0, stream>>>(
        features, label, class_sum_part, ss_parts, counts, total_parts);
    car_finalize_kernel<<<1, 1024, 0, stream>>>(class_sum_part, counts, ss_parts, total_parts, out);
}